// Round 4
// baseline (551.614 us; speedup 1.0000x reference)
//
#include <hip/hip_runtime.h>

#define T_SEQ 2048
#define DM    2048
#define NH    16
#define HD    128
#define NROW  4096   // B*T

typedef __attribute__((ext_vector_type(8))) short short8;
typedef __attribute__((ext_vector_type(4))) float f32x4;

static __device__ __forceinline__ float bf2f(unsigned short h) {
    unsigned int u = ((unsigned int)h) << 16;
    return __builtin_bit_cast(float, u);
}
static __device__ __forceinline__ unsigned short f2bf(float f) {
    unsigned int u = __builtin_bit_cast(unsigned int, f);
    u += 0x7FFFu + ((u >> 16) & 1u);
    return (unsigned short)(u >> 16);
}
// cheap round-half-up bf16 (2 VALU ops) for P/O inner-loop conversions
static __device__ __forceinline__ unsigned short bf_fast(float f) {
    return (unsigned short)((__builtin_bit_cast(unsigned int, f) + 0x8000u) >> 16);
}

typedef __attribute__((address_space(1))) const unsigned int gas_uint;
typedef __attribute__((address_space(3))) unsigned int las_uint;

static __device__ __forceinline__ void load_lds16(const void* g, void* l) {
    __builtin_amdgcn_global_load_lds((gas_uint*)g, (las_uint*)l, 16, 0, 0);
}

static __device__ __forceinline__ f32x4 mfma_bf16(short8 a, short8 b, f32x4 c) {
    return __builtin_amdgcn_mfma_f32_16x16x32_bf16(a, b, c, 0, 0, 0);
}

// ---------------- cast x -> bf16 ----------------
__global__ __launch_bounds__(256) void k_cast(const float* __restrict__ x,
                                              unsigned short* __restrict__ xb, int n) {
    int idx = (blockIdx.x * 256 + threadIdx.x) * 4;
    if (idx >= n) return;
    float4 v = *(const float4*)(x + idx);
    ushort4 o;
    o.x = f2bf(v.x); o.y = f2bf(v.y); o.z = f2bf(v.z); o.w = f2bf(v.w);
    *(ushort4*)(xb + idx) = o;
}

// ---------------- transpose+cast weights: W[k][n] f32 -> Wt[n][k] bf16 ----------------
__global__ __launch_bounds__(256) void k_transpose(const float* __restrict__ w0, const float* __restrict__ w1,
                                                   const float* __restrict__ w2, const float* __restrict__ w3,
                                                   unsigned short* __restrict__ t0, unsigned short* __restrict__ t1,
                                                   unsigned short* __restrict__ t2, unsigned short* __restrict__ t3) {
    __shared__ float tile[32][33];
    int z = blockIdx.z;
    const float* W = (z == 0) ? w0 : (z == 1) ? w1 : (z == 2) ? w2 : w3;
    unsigned short* Wt = (z == 0) ? t0 : (z == 1) ? t1 : (z == 2) ? t2 : t3;
    int bx = blockIdx.x * 32;  // n base
    int by = blockIdx.y * 32;  // k base
    int tx = threadIdx.x, ty = threadIdx.y;
#pragma unroll
    for (int i = 0; i < 4; ++i)
        tile[ty + i * 8][tx] = W[(size_t)(by + ty + i * 8) * DM + bx + tx];
    __syncthreads();
#pragma unroll
    for (int i = 0; i < 4; ++i)
        Wt[(size_t)(bx + ty + i * 8) * DM + by + tx] = f2bf(tile[tx][ty + i * 8]);
}

// ---------------- 128x128 GEMM, A[M][K] bf16 @ Bt[N][K] bf16 -> C[M][N] ----------------
template <bool FOUT>
static __device__ __forceinline__ void gemm_body(const unsigned short* __restrict__ A,
                                                 const unsigned short* __restrict__ Bt,
                                                 unsigned short* __restrict__ Cb,
                                                 float* __restrict__ Cf) {
    __shared__ unsigned short As[128 * 64];
    __shared__ unsigned short Bs[128 * 64];
    const int tid = threadIdx.x;
    const int w = tid >> 6, lane = tid & 63;
    const int col = lane & 15, quad = lane >> 4;
    const int wm = w >> 1, wn = w & 1;
    const size_t m0 = (size_t)blockIdx.y * 128;
    const size_t n0 = (size_t)blockIdx.x * 128;

    f32x4 acc[4][4];
#pragma unroll
    for (int i = 0; i < 4; ++i)
#pragma unroll
        for (int j = 0; j < 4; ++j)
            acc[i][j] = (f32x4){0.f, 0.f, 0.f, 0.f};

    const int lrow = lane >> 3;                 // 0..7 row within 8-row chunk
    const int gcol = ((lane & 7) ^ lrow) * 8;   // XOR-swizzled logical col (elems)

    for (int k0 = 0; k0 < DM; k0 += 64) {
#pragma unroll
        for (int c = w; c < 16; c += 4) {
            load_lds16(A + (m0 + c * 8 + lrow) * DM + k0 + gcol, &As[c * 512]);
            load_lds16(Bt + (n0 + c * 8 + lrow) * DM + k0 + gcol, &Bs[c * 512]);
        }
        __syncthreads();
#pragma unroll
        for (int ks = 0; ks < 2; ++ks) {
            short8 af[4], bf[4];
            int g = ks * 4 + quad;
#pragma unroll
            for (int mt = 0; mt < 4; ++mt) {
                int r = wm * 64 + mt * 16 + col;
                af[mt] = *(const short8*)&As[r * 64 + ((g ^ (r & 7)) * 8)];
            }
#pragma unroll
            for (int nt = 0; nt < 4; ++nt) {
                int r = wn * 64 + nt * 16 + col;
                bf[nt] = *(const short8*)&Bs[r * 64 + ((g ^ (r & 7)) * 8)];
            }
#pragma unroll
            for (int mt = 0; mt < 4; ++mt)
#pragma unroll
                for (int nt = 0; nt < 4; ++nt)
                    acc[mt][nt] = mfma_bf16(af[mt], bf[nt], acc[mt][nt]);
        }
        __syncthreads();
    }
#pragma unroll
    for (int mt = 0; mt < 4; ++mt)
#pragma unroll
        for (int nt = 0; nt < 4; ++nt)
#pragma unroll
            for (int reg = 0; reg < 4; ++reg) {
                size_t r = m0 + wm * 64 + mt * 16 + quad * 4 + reg;
                size_t c = n0 + wn * 64 + nt * 16 + col;
                if (FOUT) Cf[r * DM + c] = acc[mt][nt][reg];
                else      Cb[r * DM + c] = f2bf(acc[mt][nt][reg]);
            }
}

__global__ __launch_bounds__(256) void k_gemm_qkv(const unsigned short* __restrict__ xb,
                                                  const unsigned short* __restrict__ wtq,
                                                  const unsigned short* __restrict__ wtk,
                                                  const unsigned short* __restrict__ wtv,
                                                  unsigned short* __restrict__ qb,
                                                  unsigned short* __restrict__ kb,
                                                  unsigned short* __restrict__ vb) {
    int z = blockIdx.z;
    const unsigned short* Bt = (z == 0) ? wtq : (z == 1) ? wtk : wtv;
    unsigned short* C = (z == 0) ? qb : (z == 1) ? kb : vb;
    gemm_body<false>(xb, Bt, C, nullptr);
}

__global__ __launch_bounds__(256) void k_gemm_out(const unsigned short* __restrict__ ob,
                                                  const unsigned short* __restrict__ wto,
                                                  float* __restrict__ out) {
    gemm_body<true>(ob, wto, nullptr, out);
}

// ---------------- RoPE in place on K only (Q is roped in-register in k_flash) ----------------
__global__ __launch_bounds__(256) void k_rope_k(unsigned short* __restrict__ K,
                                                const float* __restrict__ cosp,
                                                const float* __restrict__ sinp) {
    int idx = blockIdx.x * 256 + threadIdx.x;   // NROW*16*16 threads
    int d4 = (idx & 15) * 4;
    int h = (idx >> 4) & 15;
    int row = idx >> 8;
    int t = row & (T_SEQ - 1);
    size_t base = (size_t)row * DM + h * HD + d4;
    ushort4 x1 = *(const ushort4*)(K + base);
    ushort4 x2 = *(const ushort4*)(K + base + 64);
    float4 c = *(const float4*)(cosp + t * 64 + d4);
    float4 s = *(const float4*)(sinp + t * 64 + d4);
    ushort4 o1, o2;
#pragma unroll
    for (int i = 0; i < 4; ++i) {
        float a1 = bf2f(((const unsigned short*)&x1)[i]);
        float a2 = bf2f(((const unsigned short*)&x2)[i]);
        float cc = ((const float*)&c)[i], ss = ((const float*)&s)[i];
        ((unsigned short*)&o1)[i] = f2bf(a1 * cc - a2 * ss);
        ((unsigned short*)&o2)[i] = f2bf(a1 * ss + a2 * cc);
    }
    *(ushort4*)(K + base) = o1;
    *(ushort4*)(K + base + 64) = o2;
}

// ---------------- V transpose: vb[b*T+t][h*128+d] -> Vt[(b*16+h)*128+d][t] ----------------
__global__ __launch_bounds__(256) void k_vtr(const unsigned short* __restrict__ V,
                                             unsigned short* __restrict__ Vt) {
    __shared__ unsigned short tile[64][68];
    int t0 = blockIdx.x * 64;
    int hd0 = blockIdx.y * 64;
    int b = blockIdx.z;
    int tid = threadIdx.x;
    int rr = tid >> 4, cc = (tid & 15) * 4;
#pragma unroll
    for (int it = 0; it < 4; ++it) {
        int row = it * 16 + rr;
        *(ushort4*)&tile[row][cc] =
            *(const ushort4*)(V + (size_t)(b * T_SEQ + t0 + row) * DM + hd0 + cc);
    }
    __syncthreads();
    int h = hd0 >> 7, d0 = hd0 & 127;
    size_t obase = (size_t)(b * NH + h) * HD;
#pragma unroll
    for (int it = 0; it < 4; ++it) {
        int lhd = it * 16 + rr;
        ushort4 v;
#pragma unroll
        for (int j = 0; j < 4; ++j) ((unsigned short*)&v)[j] = tile[cc + j][lhd];
        *(ushort4*)(Vt + (obase + d0 + lhd) * (size_t)T_SEQ + t0 + cc) = v;
    }
}

// ---------------- causal flash attention, S^T formulation, paired q-tiles ----------------
// grid (16, H, B), block 256 (4 waves). Block bx handles q-tiles bx and 31-bx.
// S^T = K·Q^T (A=K-frag shared hi/lo, B=Q-frag); softmax per-lane (col=query);
// P^T C-layout -> PV B-operand via per-wave LDS round-trip (stride 72, conflict-free);
// O^T = V^T·P^T (A=V-frag shared hi/lo).
#define PSTR 72
__global__ __launch_bounds__(256) void k_flash(const unsigned short* __restrict__ Q,
                                               const unsigned short* __restrict__ K,
                                               const unsigned short* __restrict__ Vt,
                                               unsigned short* __restrict__ O,
                                               const float* __restrict__ cosp,
                                               const float* __restrict__ sinp) {
    __shared__ unsigned short Ks[64 * 128];
    __shared__ unsigned short Vs[128 * 64];
    __shared__ unsigned short Ps[8][16 * PSTR];   // [wave] hi, [wave+4] lo
    const int tid = threadIdx.x;
    const int w = tid >> 6, lane = tid & 63;
    const int col = lane & 15, quad = lane >> 4;
    const int h = blockIdx.y, b = blockIdx.z;
    const int txlo = blockIdx.x;        // 0..15
    const int txhi = 31 - txlo;         // 16..31
    const int q0lo = txlo * 64, q0hi = txhi * 64;
    const size_t rowbase = ((size_t)b * T_SEQ) * DM + (size_t)h * HD;
    const size_t hbase = ((size_t)b * NH + h) * HD;
    const float SCL = 0.088388347648318447f * 1.4426950408889634f;  // 1/sqrt(D) * log2(e)

    unsigned short* Ph = &Ps[w][0];
    unsigned short* Pl = &Ps[w + 4][0];

    // ---- load Q fragments (B-layout: lane q=col, d=quad*8+j per 32-chunk) + RoPE ----
    short8 qlo[4], qhi[4];
    auto load_q = [&](int q0, short8* qf) {
        const int t = q0 + w * 16 + col;
        const unsigned short* qp = Q + rowbase + (size_t)t * DM;
#pragma unroll
        for (int ks = 0; ks < 4; ++ks)
            qf[ks] = *(const short8*)(qp + ks * 32 + quad * 8);
        const float* cp = cosp + t * 64 + quad * 8;
        const float* sp = sinp + t * 64 + quad * 8;
#pragma unroll
        for (int ks = 0; ks < 2; ++ks) {
            float4 c0 = *(const float4*)(cp + ks * 32);
            float4 c1 = *(const float4*)(cp + ks * 32 + 4);
            float4 s0 = *(const float4*)(sp + ks * 32);
            float4 s1 = *(const float4*)(sp + ks * 32 + 4);
#pragma unroll
            for (int j = 0; j < 8; ++j) {
                float cv = ((j < 4) ? ((const float*)&c0)[j] : ((const float*)&c1)[j - 4]) * SCL;
                float sv = ((j < 4) ? ((const float*)&s0)[j] : ((const float*)&s1)[j - 4]) * SCL;
                float a1 = bf2f((unsigned short)qf[ks][j]);
                float a2 = bf2f((unsigned short)qf[ks + 2][j]);
                qf[ks][j]     = (short)f2bf(a1 * cv - a2 * sv);
                qf[ks + 2][j] = (short)f2bf(a1 * sv + a2 * cv);
            }
        }
    };
    load_q(q0lo, qlo);
    load_q(q0hi, qhi);

    f32x4 olo[8], ohi[8];
#pragma unroll
    for (int i = 0; i < 8; ++i) {
        olo[i] = (f32x4){0.f, 0.f, 0.f, 0.f};
        ohi[i] = (f32x4){0.f, 0.f, 0.f, 0.f};
    }
    float mlo = -1e30f, llo_s = 0.f, mhi = -1e30f, lhi_s = 0.f;

    // per-lane softmax (lane holds 16 keys of one query=col), store P^T to per-wave LDS
    auto softmax_st = [&](f32x4* s, f32x4* o, float& m_i, float& l_i,
                          bool diag, int qg, int k0, unsigned short* P) {
        if (diag) {
#pragma unroll
            for (int mt = 0; mt < 4; ++mt)
#pragma unroll
                for (int reg = 0; reg < 4; ++reg)
                    if (k0 + mt * 16 + quad * 4 + reg > qg)
                        s[mt][reg] = -1e30f;
        }
        float mx = -1e30f;
#pragma unroll
        for (int mt = 0; mt < 4; ++mt)
#pragma unroll
            for (int reg = 0; reg < 4; ++reg) mx = fmaxf(mx, s[mt][reg]);
        mx = fmaxf(mx, __shfl_xor(mx, 16));
        mx = fmaxf(mx, __shfl_xor(mx, 32));
        float mnew = fmaxf(m_i, mx);
        float alpha = __builtin_amdgcn_exp2f(m_i - mnew);
        m_i = mnew;
        float sum = 0.f;
#pragma unroll
        for (int mt = 0; mt < 4; ++mt) {
            float p0 = __builtin_amdgcn_exp2f(s[mt][0] - mnew);
            float p1 = __builtin_amdgcn_exp2f(s[mt][1] - mnew);
            float p2 = __builtin_amdgcn_exp2f(s[mt][2] - mnew);
            float p3 = __builtin_amdgcn_exp2f(s[mt][3] - mnew);
            sum += (p0 + p1) + (p2 + p3);
            ushort4 st;
            ((unsigned short*)&st)[0] = bf_fast(p0);
            ((unsigned short*)&st)[1] = bf_fast(p1);
            ((unsigned short*)&st)[2] = bf_fast(p2);
            ((unsigned short*)&st)[3] = bf_fast(p3);
            *(ushort4*)(P + col * PSTR + mt * 16 + quad * 4) = st;
        }
        sum += __shfl_xor(sum, 16);
        sum += __shfl_xor(sum, 32);
        l_i = l_i * alpha + sum;
#pragma unroll
        for (int i = 0; i < 8; ++i) o[i] *= alpha;
    };

    for (int kt = 0; kt <= txhi; ++kt) {
        const int k0 = kt * 64;
        const bool lo_act = (kt <= txlo);
        __syncthreads();
        // stage K tile [64 keys][128 d] and V^T tile [128 d][64 keys], XOR-swizzled
#pragma unroll
        for (int c = 0; c < 4; ++c) {
            const int c4 = w * 4 + c;
            const int krow = c4 * 4 + (lane >> 4);
            const int kpos = lane & 15;
            load_lds16(K + rowbase + (size_t)(k0 + krow) * DM + ((kpos ^ (krow & 7)) * 8),
                       &Ks[c4 * 512]);
            const int vrow = c4 * 8 + (lane >> 3);
            const int vpos = lane & 7;
            load_lds16(Vt + (hbase + vrow) * (size_t)T_SEQ + k0 + ((vpos ^ (vrow & 7)) * 8),
                       &Vs[c4 * 512]);
        }
        __syncthreads();

        // S^T = K·Q^T : A = K-frag (shared hi/lo), B = Q-frag
        f32x4 sh[4], sl[4];
#pragma unroll
        for (int i = 0; i < 4; ++i) {
            sh[i] = (f32x4){0.f, 0.f, 0.f, 0.f};
            sl[i] = (f32x4){0.f, 0.f, 0.f, 0.f};
        }
#pragma unroll
        for (int c = 0; c < 4; ++c) {
#pragma unroll
            for (int mt = 0; mt < 4; ++mt) {
                const int key = mt * 16 + col;
                short8 kf = *(const short8*)&Ks[key * 128 + (((c * 4 + quad) ^ (key & 7)) * 8)];
                sh[mt] = mfma_bf16(kf, qhi[c], sh[mt]);
                if (lo_act) sl[mt] = mfma_bf16(kf, qlo[c], sl[mt]);
            }
        }

        softmax_st(sh, ohi, mhi, lhi_s, kt == txhi, q0hi + w * 16 + col, k0, Ph);
        if (lo_act)
            softmax_st(sl, olo, mlo, llo_s, kt == txlo, q0lo + w * 16 + col, k0, Pl);

        // O^T += V^T·P^T : A = V-frag (shared), B = P^T read back from per-wave LDS
#pragma unroll
        for (int c2 = 0; c2 < 2; ++c2) {
            short8 pbh = *(const short8*)(Ph + col * PSTR + c2 * 32 + quad * 8);
            short8 pbl;
            if (lo_act) pbl = *(const short8*)(Pl + col * PSTR + c2 * 32 + quad * 8);
#pragma unroll
            for (int mt2 = 0; mt2 < 8; ++mt2) {
                const int d = mt2 * 16 + col;
                short8 vf = *(const short8*)&Vs[d * 64 + (((c2 * 4 + quad) ^ (d & 7)) * 8)];
                ohi[mt2] = mfma_bf16(vf, pbh, ohi[mt2]);
                if (lo_act) olo[mt2] = mfma_bf16(vf, pbl, olo[mt2]);
            }
        }
    }

    // O^T C-layout: lane holds query=col, d = mt2*16 + quad*4 + reg -> ushort4 stores
    auto finish = [&](const f32x4* o, float l_i, int q0t) {
        float inv = __builtin_amdgcn_rcpf(l_i);
        unsigned short* op = O + rowbase + (size_t)(q0t + w * 16 + col) * DM + quad * 4;
#pragma unroll
        for (int mt2 = 0; mt2 < 8; ++mt2) {
            ushort4 st;
#pragma unroll
            for (int j = 0; j < 4; ++j)
                ((unsigned short*)&st)[j] = bf_fast(o[mt2][j] * inv);
            *(ushort4*)(op + mt2 * 16) = st;
        }
    };
    finish(olo, llo_s, q0lo);
    finish(ohi, lhi_s, q0hi);
}

extern "C" void kernel_launch(void* const* d_in, const int* in_sizes, int n_in,
                              void* d_out, int out_size, void* d_ws, size_t ws_size,
                              hipStream_t stream) {
    const float* x    = (const float*)d_in[0];
    // d_in[1] = mask (unused; causal structure is known)
    const float* cosp = (const float*)d_in[2];
    const float* sinp = (const float*)d_in[3];
    const float* Wq   = (const float*)d_in[4];
    const float* Wk   = (const float*)d_in[5];
    const float* Wv   = (const float*)d_in[6];
    const float* Wo   = (const float*)d_in[7];
    float* out = (float*)d_out;

    unsigned short* xb  = (unsigned short*)d_ws;             // 4096*2048 (reused as Vt later)
    unsigned short* wtq = xb  + (size_t)NROW * DM;           // 2048*2048 each
    unsigned short* wtk = wtq + (size_t)DM * DM;
    unsigned short* wtv = wtk + (size_t)DM * DM;
    unsigned short* wto = wtv + (size_t)DM * DM;
    unsigned short* qb  = wto + (size_t)DM * DM;             // 4096*2048 each
    unsigned short* kb  = qb  + (size_t)NROW * DM;
    unsigned short* vb  = kb  + (size_t)NROW * DM;
    unsigned short* ob  = vb  + (size_t)NROW * DM;
    unsigned short* vt  = xb;  // xb is dead after k_gemm_qkv; reuse for transposed V

    hipLaunchKernelGGL(k_cast, dim3(8192), dim3(256), 0, stream, x, xb, NROW * DM);
    hipLaunchKernelGGL(k_transpose, dim3(64, 64, 4), dim3(32, 8), 0, stream,
                       Wq, Wk, Wv, Wo, wtq, wtk, wtv, wto);
    hipLaunchKernelGGL(k_gemm_qkv, dim3(16, 32, 3), dim3(256), 0, stream,
                       xb, wtq, wtk, wtv, qb, kb, vb);
    hipLaunchKernelGGL(k_rope_k, dim3(4096), dim3(256), 0, stream, kb, cosp, sinp);
    hipLaunchKernelGGL(k_vtr, dim3(32, 32, 2), dim3(256), 0, stream, vb, vt);
    hipLaunchKernelGGL(k_flash, dim3(16, NH, 2), dim3(256), 0, stream,
                       qb, kb, vt, ob, cosp, sinp);
    hipLaunchKernelGGL(k_gemm_out, dim3(16, 32, 1), dim3(256), 0, stream, ob, wto, out);
}

// Round 5
// 392.226 us; speedup vs baseline: 1.4064x; 1.4064x over previous
//
#include <hip/hip_runtime.h>

#define T_SEQ 2048
#define DM    2048
#define NH    16
#define HD    128
#define NROW  4096   // B*T

typedef __attribute__((ext_vector_type(8))) short short8;
typedef __attribute__((ext_vector_type(4))) float f32x4;
typedef __attribute__((ext_vector_type(16))) float f32x16;

static __device__ __forceinline__ float bf2f(unsigned short h) {
    unsigned int u = ((unsigned int)h) << 16;
    return __builtin_bit_cast(float, u);
}
static __device__ __forceinline__ unsigned short f2bf(float f) {
    unsigned int u = __builtin_bit_cast(unsigned int, f);
    u += 0x7FFFu + ((u >> 16) & 1u);
    return (unsigned short)(u >> 16);
}
// cheap round-half-up bf16 (2 VALU ops) for P/O inner-loop conversions
static __device__ __forceinline__ unsigned short bf_fast(float f) {
    return (unsigned short)((__builtin_bit_cast(unsigned int, f) + 0x8000u) >> 16);
}

typedef __attribute__((address_space(1))) const unsigned int gas_uint;
typedef __attribute__((address_space(3))) unsigned int las_uint;

static __device__ __forceinline__ void load_lds16(const void* g, void* l) {
    __builtin_amdgcn_global_load_lds((gas_uint*)g, (las_uint*)l, 16, 0, 0);
}

static __device__ __forceinline__ f32x4 mfma_bf16(short8 a, short8 b, f32x4 c) {
    return __builtin_amdgcn_mfma_f32_16x16x32_bf16(a, b, c, 0, 0, 0);
}
static __device__ __forceinline__ f32x16 mfma32_bf16(short8 a, short8 b, f32x16 c) {
    return __builtin_amdgcn_mfma_f32_32x32x16_bf16(a, b, c, 0, 0, 0);
}

// ---------------- cast x -> bf16 ----------------
__global__ __launch_bounds__(256) void k_cast(const float* __restrict__ x,
                                              unsigned short* __restrict__ xb, int n) {
    int idx = (blockIdx.x * 256 + threadIdx.x) * 4;
    if (idx >= n) return;
    float4 v = *(const float4*)(x + idx);
    ushort4 o;
    o.x = f2bf(v.x); o.y = f2bf(v.y); o.z = f2bf(v.z); o.w = f2bf(v.w);
    *(ushort4*)(xb + idx) = o;
}

// ---------------- transpose+cast weights: W[k][n] f32 -> Wt[n][k] bf16 ----------------
__global__ __launch_bounds__(256) void k_transpose(const float* __restrict__ w0, const float* __restrict__ w1,
                                                   const float* __restrict__ w2, const float* __restrict__ w3,
                                                   unsigned short* __restrict__ t0, unsigned short* __restrict__ t1,
                                                   unsigned short* __restrict__ t2, unsigned short* __restrict__ t3) {
    __shared__ float tile[32][33];
    int z = blockIdx.z;
    const float* W = (z == 0) ? w0 : (z == 1) ? w1 : (z == 2) ? w2 : w3;
    unsigned short* Wt = (z == 0) ? t0 : (z == 1) ? t1 : (z == 2) ? t2 : t3;
    int bx = blockIdx.x * 32;  // n base
    int by = blockIdx.y * 32;  // k base
    int tx = threadIdx.x, ty = threadIdx.y;
#pragma unroll
    for (int i = 0; i < 4; ++i)
        tile[ty + i * 8][tx] = W[(size_t)(by + ty + i * 8) * DM + bx + tx];
    __syncthreads();
#pragma unroll
    for (int i = 0; i < 4; ++i)
        Wt[(size_t)(bx + ty + i * 8) * DM + by + tx] = f2bf(tile[tx][ty + i * 8]);
}

// ---------------- 128x128 GEMM, A[M][K] bf16 @ Bt[N][K] bf16 -> C[M][N] ----------------
template <bool FOUT>
static __device__ __forceinline__ void gemm_body(const unsigned short* __restrict__ A,
                                                 const unsigned short* __restrict__ Bt,
                                                 unsigned short* __restrict__ Cb,
                                                 float* __restrict__ Cf) {
    __shared__ unsigned short As[128 * 64];
    __shared__ unsigned short Bs[128 * 64];
    const int tid = threadIdx.x;
    const int w = tid >> 6, lane = tid & 63;
    const int col = lane & 15, quad = lane >> 4;
    const int wm = w >> 1, wn = w & 1;
    const size_t m0 = (size_t)blockIdx.y * 128;
    const size_t n0 = (size_t)blockIdx.x * 128;

    f32x4 acc[4][4];
#pragma unroll
    for (int i = 0; i < 4; ++i)
#pragma unroll
        for (int j = 0; j < 4; ++j)
            acc[i][j] = (f32x4){0.f, 0.f, 0.f, 0.f};

    const int lrow = lane >> 3;                 // 0..7 row within 8-row chunk
    const int gcol = ((lane & 7) ^ lrow) * 8;   // XOR-swizzled logical col (elems)

    for (int k0 = 0; k0 < DM; k0 += 64) {
#pragma unroll
        for (int c = w; c < 16; c += 4) {
            load_lds16(A + (m0 + c * 8 + lrow) * DM + k0 + gcol, &As[c * 512]);
            load_lds16(Bt + (n0 + c * 8 + lrow) * DM + k0 + gcol, &Bs[c * 512]);
        }
        __syncthreads();
#pragma unroll
        for (int ks = 0; ks < 2; ++ks) {
            short8 af[4], bf[4];
            int g = ks * 4 + quad;
#pragma unroll
            for (int mt = 0; mt < 4; ++mt) {
                int r = wm * 64 + mt * 16 + col;
                af[mt] = *(const short8*)&As[r * 64 + ((g ^ (r & 7)) * 8)];
            }
#pragma unroll
            for (int nt = 0; nt < 4; ++nt) {
                int r = wn * 64 + nt * 16 + col;
                bf[nt] = *(const short8*)&Bs[r * 64 + ((g ^ (r & 7)) * 8)];
            }
#pragma unroll
            for (int mt = 0; mt < 4; ++mt)
#pragma unroll
                for (int nt = 0; nt < 4; ++nt)
                    acc[mt][nt] = mfma_bf16(af[mt], bf[nt], acc[mt][nt]);
        }
        __syncthreads();
    }
#pragma unroll
    for (int mt = 0; mt < 4; ++mt)
#pragma unroll
        for (int nt = 0; nt < 4; ++nt)
#pragma unroll
            for (int reg = 0; reg < 4; ++reg) {
                size_t r = m0 + wm * 64 + mt * 16 + quad * 4 + reg;
                size_t c = n0 + wn * 64 + nt * 16 + col;
                if (FOUT) Cf[r * DM + c] = acc[mt][nt][reg];
                else      Cb[r * DM + c] = f2bf(acc[mt][nt][reg]);
            }
}

__global__ __launch_bounds__(256) void k_gemm_qkv(const unsigned short* __restrict__ xb,
                                                  const unsigned short* __restrict__ wtq,
                                                  const unsigned short* __restrict__ wtk,
                                                  const unsigned short* __restrict__ wtv,
                                                  unsigned short* __restrict__ qb,
                                                  unsigned short* __restrict__ kb,
                                                  unsigned short* __restrict__ vb) {
    int z = blockIdx.z;
    const unsigned short* Bt = (z == 0) ? wtq : (z == 1) ? wtk : wtv;
    unsigned short* C = (z == 0) ? qb : (z == 1) ? kb : vb;
    gemm_body<false>(xb, Bt, C, nullptr);
}

__global__ __launch_bounds__(256) void k_gemm_out(const unsigned short* __restrict__ ob,
                                                  const unsigned short* __restrict__ wto,
                                                  float* __restrict__ out) {
    gemm_body<true>(ob, wto, nullptr, out);
}

// ---------------- RoPE in place on K only (Q is roped in-register in k_flash) ----------------
__global__ __launch_bounds__(256) void k_rope_k(unsigned short* __restrict__ K,
                                                const float* __restrict__ cosp,
                                                const float* __restrict__ sinp) {
    int idx = blockIdx.x * 256 + threadIdx.x;   // NROW*16*16 threads
    int d4 = (idx & 15) * 4;
    int h = (idx >> 4) & 15;
    int row = idx >> 8;
    int t = row & (T_SEQ - 1);
    size_t base = (size_t)row * DM + h * HD + d4;
    ushort4 x1 = *(const ushort4*)(K + base);
    ushort4 x2 = *(const ushort4*)(K + base + 64);
    float4 c = *(const float4*)(cosp + t * 64 + d4);
    float4 s = *(const float4*)(sinp + t * 64 + d4);
    ushort4 o1, o2;
#pragma unroll
    for (int i = 0; i < 4; ++i) {
        float a1 = bf2f(((const unsigned short*)&x1)[i]);
        float a2 = bf2f(((const unsigned short*)&x2)[i]);
        float cc = ((const float*)&c)[i], ss = ((const float*)&s)[i];
        ((unsigned short*)&o1)[i] = f2bf(a1 * cc - a2 * ss);
        ((unsigned short*)&o2)[i] = f2bf(a1 * ss + a2 * cc);
    }
    *(ushort4*)(K + base) = o1;
    *(ushort4*)(K + base + 64) = o2;
}

// ---------------- V transpose: vb[b*T+t][h*128+d] -> Vt[(b*16+h)*128+d][t] ----------------
__global__ __launch_bounds__(256) void k_vtr(const unsigned short* __restrict__ V,
                                             unsigned short* __restrict__ Vt) {
    __shared__ unsigned short tile[64][68];
    int t0 = blockIdx.x * 64;
    int hd0 = blockIdx.y * 64;
    int b = blockIdx.z;
    int tid = threadIdx.x;
    int rr = tid >> 4, cc = (tid & 15) * 4;
#pragma unroll
    for (int it = 0; it < 4; ++it) {
        int row = it * 16 + rr;
        *(ushort4*)&tile[row][cc] =
            *(const ushort4*)(V + (size_t)(b * T_SEQ + t0 + row) * DM + hd0 + cc);
    }
    __syncthreads();
    int h = hd0 >> 7, d0 = hd0 & 127;
    size_t obase = (size_t)(b * NH + h) * HD;
#pragma unroll
    for (int it = 0; it < 4; ++it) {
        int lhd = it * 16 + rr;
        ushort4 v;
#pragma unroll
        for (int j = 0; j < 4; ++j) ((unsigned short*)&v)[j] = tile[cc + j][lhd];
        *(ushort4*)(Vt + (obase + d0 + lhd) * (size_t)T_SEQ + t0 + cc) = v;
    }
}

// ---------------- causal flash attention, 32x32x16 MFMA, S^T formulation ----------------
// grid flat 512 blocks; LPT remap: j = 15 - (flat>>5) so longest blocks dispatch first.
// Block = 128 queries (4 waves x 32). Wave: S^T = K·Q^T (A=K-frag, B=Q-frag);
// per-lane softmax (col=query, 32 in-lane keys + shfl_xor(32));
// P^T -> per-wave LDS -> B-operand; O^T = V^T·P^T.
#define PST 72
__global__ __launch_bounds__(256) void k_flash(const unsigned short* __restrict__ Q,
                                               const unsigned short* __restrict__ K,
                                               const unsigned short* __restrict__ Vt,
                                               unsigned short* __restrict__ O,
                                               const float* __restrict__ cosp,
                                               const float* __restrict__ sinp) {
    __shared__ unsigned short Ks[64 * 128];
    __shared__ unsigned short Vs[128 * 64];
    __shared__ unsigned short Ps[4][32 * PST];
    const int tid = threadIdx.x;
    const int w = tid >> 6, lane = tid & 63;
    const int col = lane & 31, l5 = lane >> 5;
    const int flat = blockIdx.x | (blockIdx.y << 4) | (blockIdx.z << 8);
    const int j = 15 - (flat >> 5);
    const int hb = flat & 31;
    const int h = hb & 15, b = hb >> 4;
    const int q0 = j * 128;
    const size_t rowbase = ((size_t)b * T_SEQ) * DM + (size_t)h * HD;
    const size_t hbase = ((size_t)b * NH + h) * HD;
    const float SCL = 0.088388347648318447f * 1.4426950408889634f;  // 1/sqrt(D) * log2(e)
    unsigned short* Pw = &Ps[w][0];

    const int t = q0 + w * 32 + col;     // this lane's query
    // ---- load Q fragments (B-layout: q=col, k=l5*8+jj per 16-chunk) + in-reg RoPE ----
    short8 qf[8];
    {
        const unsigned short* qp = Q + rowbase + (size_t)t * DM + l5 * 8;
#pragma unroll
        for (int st = 0; st < 8; ++st)
            qf[st] = *(const short8*)(qp + st * 16);
        const float* cp = cosp + t * 64 + l5 * 8;
        const float* sp = sinp + t * 64 + l5 * 8;
#pragma unroll
        for (int st = 0; st < 4; ++st) {
            float4 c0 = *(const float4*)(cp + st * 16);
            float4 c1 = *(const float4*)(cp + st * 16 + 4);
            float4 s0v = *(const float4*)(sp + st * 16);
            float4 s1v = *(const float4*)(sp + st * 16 + 4);
#pragma unroll
            for (int jj = 0; jj < 8; ++jj) {
                float cv = ((jj < 4) ? ((const float*)&c0)[jj] : ((const float*)&c1)[jj - 4]) * SCL;
                float sv = ((jj < 4) ? ((const float*)&s0v)[jj] : ((const float*)&s1v)[jj - 4]) * SCL;
                float a1 = bf2f((unsigned short)qf[st][jj]);
                float a2 = bf2f((unsigned short)qf[st + 4][jj]);
                qf[st][jj]     = (short)f2bf(a1 * cv - a2 * sv);
                qf[st + 4][jj] = (short)f2bf(a1 * sv + a2 * cv);
            }
        }
    }

    f32x16 o[4];
#pragma unroll
    for (int i = 0; i < 4; ++i) o[i] = (f32x16)(0.f);
    float m_i = -1e30f, l_i = 0.f;

    const int kt_max = 2 * j + 1;
    const int kt_lim = (q0 + w * 32 + 31) >> 6;   // last k-tile this wave computes
    const int cswz = col & 7;

    for (int kt = 0; kt <= kt_max; ++kt) {
        const int k0 = kt * 64;
        __syncthreads();
        // stage K tile [64 keys][128 d] and V^T tile [128 d][64 keys], XOR-swizzled
#pragma unroll
        for (int c = 0; c < 4; ++c) {
            const int c4 = w * 4 + c;
            const int krow = c4 * 4 + (lane >> 4);
            const int kpos = lane & 15;
            load_lds16(K + rowbase + (size_t)(k0 + krow) * DM + ((kpos ^ (krow & 7)) * 8),
                       &Ks[c4 * 512]);
            const int vrow = c4 * 8 + (lane >> 3);
            const int vpos = lane & 7;
            load_lds16(Vt + (hbase + vrow) * (size_t)T_SEQ + k0 + ((vpos ^ (vrow & 7)) * 8),
                       &Vs[c4 * 512]);
        }
        __syncthreads();
        if (kt > kt_lim) continue;   // wave-uniform; barriers still hit each iter

        // S^T = K·Q^T : two 32-key M-subtiles, 8 k-steps over D=128
        f32x16 s0 = (f32x16)(0.f), s1 = (f32x16)(0.f);
#pragma unroll
        for (int st = 0; st < 8; ++st) {
            const int dg = (2 * st + l5) ^ cswz;
            short8 kf0 = *(const short8*)&Ks[col * 128 + dg * 8];
            short8 kf1 = *(const short8*)&Ks[col * 128 + 4096 + dg * 8];
            s0 = mfma32_bf16(kf0, qf[st], s0);
            s1 = mfma32_bf16(kf1, qf[st], s1);
        }

        // causal mask (diag tiles only)
        if (k0 + 63 > q0 + w * 32) {
            const int kb = k0 + 4 * l5;
#pragma unroll
            for (int r = 0; r < 16; ++r) {
                const int key = kb + (r & 3) + 8 * (r >> 2);
                if (key > t) s0[r] = -1e30f;
                if (key + 32 > t) s1[r] = -1e30f;
            }
        }

        // per-lane online softmax (query=col; 32 in-lane keys + l5 partner)
        float mx = -1e30f;
#pragma unroll
        for (int r = 0; r < 16; ++r) mx = fmaxf(mx, fmaxf(s0[r], s1[r]));
        mx = fmaxf(mx, __shfl_xor(mx, 32));
        const float mnew = fmaxf(m_i, mx);
        const float alpha = __builtin_amdgcn_exp2f(m_i - mnew);
        m_i = mnew;
        float sum = 0.f;
#pragma unroll
        for (int r = 0; r < 16; ++r) {
            float p0 = __builtin_amdgcn_exp2f(s0[r] - mnew);
            float p1 = __builtin_amdgcn_exp2f(s1[r] - mnew);
            s0[r] = p0; s1[r] = p1;
            sum += p0 + p1;
        }
        sum += __shfl_xor(sum, 32);
        l_i = l_i * alpha + sum;
#pragma unroll
        for (int i = 0; i < 4; ++i) o[i] *= alpha;

        // P^T -> per-wave LDS (runs of 4 consecutive keys per C-reg group)
#pragma unroll
        for (int g = 0; g < 4; ++g) {
            ushort4 a4, b4;
#pragma unroll
            for (int i = 0; i < 4; ++i) {
                ((unsigned short*)&a4)[i] = bf_fast(s0[g * 4 + i]);
                ((unsigned short*)&b4)[i] = bf_fast(s1[g * 4 + i]);
            }
            *(ushort4*)(Pw + col * PST + g * 8 + 4 * l5)      = a4;
            *(ushort4*)(Pw + col * PST + 32 + g * 8 + 4 * l5) = b4;
        }
        // read back as B-frags: keys st*16 + l5*8 + {0..7} for query col
        short8 pb[4];
#pragma unroll
        for (int st = 0; st < 4; ++st)
            pb[st] = *(const short8*)(Pw + col * PST + st * 16 + l5 * 8);

        // O^T += V^T·P^T : A = V-frag (d rows), B = P-frag
#pragma unroll
        for (int ms = 0; ms < 4; ++ms) {
            const int drow = (ms * 32 + col) * 64;
#pragma unroll
            for (int st = 0; st < 4; ++st) {
                const int kg = (2 * st + l5) ^ cswz;
                short8 vf = *(const short8*)&Vs[drow + kg * 8];
                o[ms] = mfma32_bf16(vf, pb[st], o[ms]);
            }
        }
    }

    // epilogue: lane holds query=col, d = ms*32 + g*8 + 4*l5 + {0..3}
    const float inv = __builtin_amdgcn_rcpf(l_i);
    unsigned short* op = O + rowbase + (size_t)t * DM;
#pragma unroll
    for (int ms = 0; ms < 4; ++ms)
#pragma unroll
        for (int g = 0; g < 4; ++g) {
            ushort4 st4;
#pragma unroll
            for (int i = 0; i < 4; ++i)
                ((unsigned short*)&st4)[i] = bf_fast(o[ms][g * 4 + i] * inv);
            *(ushort4*)(op + ms * 32 + g * 8 + 4 * l5) = st4;
        }
}

extern "C" void kernel_launch(void* const* d_in, const int* in_sizes, int n_in,
                              void* d_out, int out_size, void* d_ws, size_t ws_size,
                              hipStream_t stream) {
    const float* x    = (const float*)d_in[0];
    // d_in[1] = mask (unused; causal structure is known)
    const float* cosp = (const float*)d_in[2];
    const float* sinp = (const float*)d_in[3];
    const float* Wq   = (const float*)d_in[4];
    const float* Wk   = (const float*)d_in[5];
    const float* Wv   = (const float*)d_in[6];
    const float* Wo   = (const float*)d_in[7];
    float* out = (float*)d_out;

    unsigned short* xb  = (unsigned short*)d_ws;             // 4096*2048 (reused as Vt later)
    unsigned short* wtq = xb  + (size_t)NROW * DM;           // 2048*2048 each
    unsigned short* wtk = wtq + (size_t)DM * DM;
    unsigned short* wtv = wtk + (size_t)DM * DM;
    unsigned short* wto = wtv + (size_t)DM * DM;
    unsigned short* qb  = wto + (size_t)DM * DM;             // 4096*2048 each
    unsigned short* kb  = qb  + (size_t)NROW * DM;
    unsigned short* vb  = kb  + (size_t)NROW * DM;
    unsigned short* ob  = vb  + (size_t)NROW * DM;
    unsigned short* vt  = xb;  // xb is dead after k_gemm_qkv; reuse for transposed V

    hipLaunchKernelGGL(k_cast, dim3(8192), dim3(256), 0, stream, x, xb, NROW * DM);
    hipLaunchKernelGGL(k_transpose, dim3(64, 64, 4), dim3(32, 8), 0, stream,
                       Wq, Wk, Wv, Wo, wtq, wtk, wtv, wto);
    hipLaunchKernelGGL(k_gemm_qkv, dim3(16, 32, 3), dim3(256), 0, stream,
                       xb, wtq, wtk, wtv, qb, kb, vb);
    hipLaunchKernelGGL(k_rope_k, dim3(4096), dim3(256), 0, stream, kb, cosp, sinp);
    hipLaunchKernelGGL(k_vtr, dim3(32, 32, 2), dim3(256), 0, stream, vb, vt);
    hipLaunchKernelGGL(k_flash, dim3(16, 16, 2), dim3(256), 0, stream,
                       qb, kb, vt, ob, cosp, sinp);
    hipLaunchKernelGGL(k_gemm_out, dim3(16, 32, 1), dim3(256), 0, stream, ob, wto, out);
}